// Round 5
// baseline (1044.158 us; speedup 1.0000x reference)
//
#include <hip/hip_runtime.h>

// Decoder layer: x -> rms -> QKV -> causal attn -> +x@wo -> rms -> SwiGLU -> +down
// B=2 S=2048 H=2048 NH=16 HD=128 FF=8192, fp32 I/O, bf16 MFMA compute.

#define HH 2048
#define FF 8192
#define BB 2
#define SS 2048
#define NHH 16
#define HDD 128
#define MM (BB * SS)  // 4096 rows

typedef __attribute__((ext_vector_type(8))) short short8;
typedef __attribute__((ext_vector_type(4))) short short4v;
typedef __attribute__((ext_vector_type(4))) float f32x4;

#define DEV __device__ __forceinline__

DEV short f2bf(float f) {  // RNE f32->bf16
  unsigned u = __builtin_bit_cast(unsigned, f);
  u += 0x7fffu + ((u >> 16) & 1u);
  return (short)(u >> 16);
}
DEV float bf2f(short s) {
  unsigned u = ((unsigned)(unsigned short)s) << 16;
  return __builtin_bit_cast(float, u);
}

// async global->LDS, 16B per lane; lds ptr must be wave-uniform, HW adds lane*16
#define GLL16(gp, lp)                                                    \
  __builtin_amdgcn_global_load_lds(                                      \
      (const __attribute__((address_space(1))) void*)(gp),               \
      (__attribute__((address_space(3))) void*)(lp), 16, 0, 0)

// ---------------- weight transpose + cast: W[K][N] f32 -> Wt[N][K] bf16 -----
__global__ __launch_bounds__(256) void transpose_cast(
    const float* __restrict__ W, short* __restrict__ Wt, int K, int N) {
  __shared__ float tile[32][33];
  int n0 = blockIdx.x * 32, k0 = blockIdx.y * 32;
  int tx = threadIdx.x & 31, ty = threadIdx.x >> 5;
#pragma unroll
  for (int i = 0; i < 32; i += 8)
    tile[ty + i][tx] = W[(long)(k0 + ty + i) * N + n0 + tx];
  __syncthreads();
#pragma unroll
  for (int i = 0; i < 32; i += 8)
    Wt[(long)(n0 + ty + i) * K + k0 + tx] = f2bf(tile[tx][ty + i]);
}

// ---------------- RMSNorm row kernel: f32 in -> bf16 out --------------------
__global__ __launch_bounds__(256) void rmsnorm_k(const float* __restrict__ x,
                                                 const float* __restrict__ g,
                                                 short* __restrict__ out) {
  int row = blockIdx.x;
  int t = threadIdx.x;
  const float* xr = x + (long)row * HH;
  f32x4 v0 = *(const f32x4*)(xr + t * 4);
  f32x4 v1 = *(const f32x4*)(xr + 1024 + t * 4);
  float ss = v0[0] * v0[0] + v0[1] * v0[1] + v0[2] * v0[2] + v0[3] * v0[3] +
             v1[0] * v1[0] + v1[1] * v1[1] + v1[2] * v1[2] + v1[3] * v1[3];
#pragma unroll
  for (int off = 1; off < 64; off <<= 1) ss += __shfl_xor(ss, off);
  __shared__ float red[4];
  if ((t & 63) == 0) red[t >> 6] = ss;
  __syncthreads();
  float tot = red[0] + red[1] + red[2] + red[3];
  float rs = rsqrtf(tot * (1.0f / HH) + 1e-6f);
  f32x4 g0 = *(const f32x4*)(g + t * 4);
  f32x4 g1 = *(const f32x4*)(g + 1024 + t * 4);
  short4v o0, o1;
#pragma unroll
  for (int e = 0; e < 4; ++e) {
    o0[e] = f2bf(v0[e] * rs * g0[e]);
    o1[e] = f2bf(v1[e] * rs * g1[e]);
  }
  *(short4v*)(out + (long)row * HH + t * 4) = o0;
  *(short4v*)(out + (long)row * HH + 1024 + t * 4) = o1;
}

// ---------------- bf16 MFMA GEMM (m97 128x128, 2-phase) ---------------------
// EPI: 0 plain bf16 [M][N]; 1 bf16 per-head [b,h,s,d]; 2 bf16 Vt [b,h,d,s];
//      3 f32 out = aux(f32)[M][N] + acc; 4 bf16 out = silu(aux bf16)*acc.
template <int EPI>
__global__ __launch_bounds__(256) void gemm_bt(const short* __restrict__ A,
                                               const short* __restrict__ Bt,
                                               int M, int N, int K,
                                               void* out, const void* aux) {
  __shared__ short As[128 * 64];
  __shared__ short Bs[128 * 64];
  int nbn = N >> 7;
  int nwg = gridDim.x;
  int bid = blockIdx.x;
  int qq = nwg >> 3, rr = nwg & 7;
  int xcd = bid & 7, lid = bid >> 3;
  int wg = (xcd < rr ? xcd * (qq + 1) : rr * (qq + 1) + (xcd - rr) * qq) + lid;
  int bm = wg / nbn, bn = wg % nbn;
  int t = threadIdx.x, w = t >> 6, lane = t & 63, lg = lane >> 4, c = lane & 15;
  int wr = w >> 1, wc = w & 1;
  const short* Abase = A + (long)bm * 128 * K;
  const short* Bbase = Bt + (long)bn * 128 * K;
  f32x4 acc[4][4] = {};
  int nk = K >> 6;
  for (int kt = 0; kt < nk; ++kt) {
    int k0 = kt << 6;
    __syncthreads();
#pragma unroll
    for (int i = 0; i < 4; ++i) {
      int idx = i * 256 + t;
      int row = idx >> 3, p = idx & 7;
      int col = k0 + ((p ^ (row & 7)) << 3);
      GLL16(Abase + (long)row * K + col, As + (i * 256 + w * 64) * 8);
      GLL16(Bbase + (long)row * K + col, Bs + (i * 256 + w * 64) * 8);
    }
    __syncthreads();
#pragma unroll
    for (int kk = 0; kk < 2; ++kk) {
      short8 af[4], bfr[4];
#pragma unroll
      for (int m = 0; m < 4; ++m) {
        int row = wr * 64 + m * 16 + c;
        af[m] = *(const short8*)(As + row * 64 + ((((kk << 2) | lg) ^ (row & 7)) << 3));
      }
#pragma unroll
      for (int n = 0; n < 4; ++n) {
        int row = wc * 64 + n * 16 + c;
        bfr[n] = *(const short8*)(Bs + row * 64 + ((((kk << 2) | lg) ^ (row & 7)) << 3));
      }
#pragma unroll
      for (int m = 0; m < 4; ++m)
#pragma unroll
        for (int n = 0; n < 4; ++n)
          acc[m][n] = __builtin_amdgcn_mfma_f32_16x16x32_bf16(af[m], bfr[n], acc[m][n], 0, 0, 0);
    }
  }
#pragma unroll
  for (int m = 0; m < 4; ++m) {
#pragma unroll
    for (int n = 0; n < 4; ++n) {
      int rL = wr * 64 + m * 16 + lg * 4;
      int cL = wc * 64 + n * 16 + c;
      long rg = (long)bm * 128 + rL;
      long cg = (long)bn * 128 + cL;
      if (EPI == 2) {
        int b = (int)(rg >> 11), s = (int)(rg & 2047);
        int head = (int)(cg >> 7), d = (int)(cg & 127);
        short4v pk;
#pragma unroll
        for (int j = 0; j < 4; ++j) pk[j] = f2bf(acc[m][n][j]);
        *(short4v*)((short*)out + ((long)(b * NHH + head) * HDD + d) * SS + s) = pk;
      } else {
#pragma unroll
        for (int j = 0; j < 4; ++j) {
          long r = rg + j;
          float v = acc[m][n][j];
          if (EPI == 0) {
            ((short*)out)[r * N + cg] = f2bf(v);
          } else if (EPI == 1) {
            int b = (int)(r >> 11), s = (int)(r & 2047);
            int head = (int)(cg >> 7), d = (int)(cg & 127);
            ((short*)out)[((long)(b * NHH + head) * SS + s) * HDD + d] = f2bf(v);
          } else if (EPI == 3) {
            ((float*)out)[r * N + cg] = ((const float*)aux)[r * N + cg] + v;
          } else if (EPI == 4) {
            float gv = bf2f(((const short*)aux)[r * N + cg]);
            float sg = gv / (1.0f + __expf(-gv));
            ((short*)out)[r * N + cg] = f2bf(sg * v);
          }
        }
      }
    }
  }
}

// ---------------- 256x256 8-phase GEMM, R5: one-phase register lookahead ----
// Reads lead their consuming MFMA by >=1 phase so the LDS drain of phase p's
// reads overlaps phase p's MFMA cluster (the R3/R4 versions serialized them).
// Read schedule (tile t): phi1: A1(t),B1(t); phi2: B0(t+1); phi3: A0(t+1).
// MFMA: phi1: Q1=(a0,b0cur); phi2: Q2=(a0,b1); phi3: Q3=(a1,b1); phi4: Q4=(a1,b0cur).
// Stage schedule unchanged: phi1: B1(t+1)->buf^1; phi2..4: A0,B0,A1(t+2)->buf.
// vmcnt(4) at phi2 retires A0/B0(t+1); vmcnt(6) at phi4 retires A1/B1(t+1).
// Steady state: 6 loads (3 half-tiles) in flight. b0 double-buffered in regs
// (compile-time swap via x2 unroll). All hazards >=1 barrier apart.
template <int MH, int NHF>
DEV void mfma_quad(f32x4 (&acc)[8][4], const short8 (&a)[4][2],
                   const short8 (&bb)[2][2]) {
  __builtin_amdgcn_s_setprio(1);
#pragma unroll
  for (int kk = 0; kk < 2; ++kk)
#pragma unroll
    for (int i = 0; i < 4; ++i)
#pragma unroll
      for (int n2 = 0; n2 < 2; ++n2)
        acc[MH * 4 + i][NHF * 2 + n2] = __builtin_amdgcn_mfma_f32_16x16x32_bf16(
            a[i][kk], bb[n2][kk], acc[MH * 4 + i][NHF * 2 + n2], 0, 0, 0);
  __builtin_amdgcn_s_setprio(0);
}

#define SBAR()                          \
  __builtin_amdgcn_sched_barrier(0);    \
  __builtin_amdgcn_s_barrier()

template <int EPI>
__global__ __launch_bounds__(512, 1) void gemm256(const short* __restrict__ A,
                                                  const short* __restrict__ Bt,
                                                  int M, int N, int K,
                                                  void* out, const void* aux) {
  __shared__ short As[2][2][128 * 64];
  __shared__ short Bs[2][2][128 * 64];
  int nbn = N >> 8;
  int nwg = gridDim.x;
  int bid = blockIdx.x;
  int qq = nwg >> 3, rr = nwg & 7;
  int xcd = bid & 7, lid = bid >> 3;
  int wg = (xcd < rr ? xcd * (qq + 1) : rr * (qq + 1) + (xcd - rr) * qq) + lid;
  int bm = wg / nbn, bn = wg % nbn;
  int tid = threadIdx.x, w = tid >> 6, lane = tid & 63, lg = lane >> 4, cl = lane & 15;
  int wr = w >> 2, wc = w & 3;
  const short* Abase = A + (long)bm * 256 * K;
  const short* Bbase = Bt + (long)bn * 256 * K;

  f32x4 acc[8][4] = {};
  short8 a0[4][2], a1[4][2], b0A[2][2], b0B[2][2], b1[2][2];
  int nk = K >> 6;  // nk even, >= 4 (K=2048/8192 -> 32/128)

  // loop-invariant LDS read offsets (elements within an As/Bs half block)
  int offA[4][2], offB[2][2];
#pragma unroll
  for (int i = 0; i < 4; ++i)
#pragma unroll
    for (int kk = 0; kk < 2; ++kk) {
      int rho = wr * 64 + i * 16 + cl;
      offA[i][kk] = rho * 64 + ((((kk << 2) | lg) ^ (rho & 7)) << 3);
    }
#pragma unroll
  for (int n2 = 0; n2 < 2; ++n2)
#pragma unroll
    for (int kk = 0; kk < 2; ++kk) {
      int rho = wc * 32 + n2 * 16 + cl;
      offB[n2][kk] = rho * 64 + ((((kk << 2) | lg) ^ (rho & 7)) << 3);
    }

  // loop-invariant stage source pointers (add k0 per call)
  const short* srcA[2][2];  // [mh][q]
  const short* srcB[2][2];  // [nh][q]
#pragma unroll
  for (int q = 0; q < 2; ++q) {
    int sg = q * 512 + tid;
    int rho = sg >> 3, p = sg & 7;
    int swz = (p ^ (rho & 7)) << 3;
#pragma unroll
    for (int mh = 0; mh < 2; ++mh) {
      int growA = ((rho >> 6) << 7) + (mh << 6) + (rho & 63);
      srcA[mh][q] = Abase + (long)growA * K + swz;
      int growB = ((rho >> 5) << 6) + (mh << 5) + (rho & 31);
      srcB[mh][q] = Bbase + (long)growB * K + swz;
    }
  }
  auto stA = [&](int kt, int cb, int mh) {
    int k0 = kt << 6;
    GLL16(srcA[mh][0] + k0, &As[cb][mh][w * 512]);
    GLL16(srcA[mh][1] + k0, &As[cb][mh][4096 + w * 512]);
  };
  auto stB = [&](int kt, int cb, int nh) {
    int k0 = kt << 6;
    GLL16(srcB[nh][0] + k0, &Bs[cb][nh][w * 512]);
    GLL16(srcB[nh][1] + k0, &Bs[cb][nh][4096 + w * 512]);
  };
  auto LDA = [&](const short* base, short8(&dst)[4][2]) {
#pragma unroll
    for (int i = 0; i < 4; ++i)
#pragma unroll
      for (int kk = 0; kk < 2; ++kk)
        dst[i][kk] = *(const short8*)(base + offA[i][kk]);
  };
  auto LDB = [&](const short* base, short8(&dst)[2][2]) {
#pragma unroll
    for (int n2 = 0; n2 < 2; ++n2)
#pragma unroll
      for (int kk = 0; kk < 2; ++kk)
        dst[n2][kk] = *(const short8*)(base + offB[n2][kk]);
  };

  // prologue: tile0 fully + tile1 {A0,A1,B0}; B1(1) issues in t=0 phi1.
  stA(0, 0, 0); stA(0, 0, 1); stB(0, 0, 0); stB(0, 0, 1);
  stA(1, 1, 0); stA(1, 1, 1); stB(1, 1, 0);
  asm volatile("s_waitcnt vmcnt(6)" ::: "memory");
  SBAR();
  // pre-read Q1(0) operands
  LDA(&As[0][0][0], a0);
  LDB(&Bs[0][0][0], b0A);

#define TILE_BODY(T, C, B0C, B0N)                                    \
  {                                                                  \
    int t1 = (T) + 1 < nk ? (T) + 1 : (T) + 1 - nk;                  \
    int t2 = (T) + 2 < nk ? (T) + 2 : (T) + 2 - nk;                  \
    /* phi1: reads A1(t),B1(t); MFMA Q1 */                           \
    LDA(&As[C][1][0], a1);                                           \
    LDB(&Bs[C][1][0], b1);                                           \
    stB(t1, (C) ^ 1, 1);                                             \
    SBAR();                                                          \
    mfma_quad<0, 0>(acc, a0, B0C);                                   \
    SBAR();                                                          \
    /* phi2: vmcnt(4) retires A0/B0(t+1); read B0(t+1); MFMA Q2 */   \
    asm volatile("s_waitcnt vmcnt(4)" ::: "memory");                 \
    LDB(&Bs[(C) ^ 1][0][0], B0N);                                    \
    stA(t2, C, 0);                                                   \
    SBAR();                                                          \
    mfma_quad<0, 1>(acc, a0, b1);                                    \
    SBAR();                                                          \
    /* phi3: read A0(t+1); MFMA Q3 */                                \
    LDA(&As[(C) ^ 1][0][0], a0);                                     \
    stB(t2, C, 0);                                                   \
    SBAR();                                                          \
    mfma_quad<1, 1>(acc, a1, b1);                                    \
    SBAR();                                                          \
    /* phi4: vmcnt(6) retires A1/B1(t+1); MFMA Q4 */                 \
    stA(t2, C, 1);                                                   \
    asm volatile("s_waitcnt vmcnt(6)" ::: "memory");                 \
    SBAR();                                                          \
    mfma_quad<1, 0>(acc, a1, B0C);                                   \
    SBAR();                                                          \
  }

  for (int t = 0; t < nk; t += 2) {
    TILE_BODY(t, 0, b0A, b0B)
    TILE_BODY(t + 1, 1, b0B, b0A)
  }
#undef TILE_BODY
  asm volatile("s_waitcnt vmcnt(0)" ::: "memory");

  // epilogue
#pragma unroll
  for (int m = 0; m < 8; ++m) {
#pragma unroll
    for (int n = 0; n < 4; ++n) {
      long rgb = (long)bm * 256 + wr * 128 + m * 16 + lg * 4;
      long cg = (long)bn * 256 + wc * 64 + n * 16 + cl;
#pragma unroll
      for (int j = 0; j < 4; ++j) {
        long r = rgb + j;
        float v = acc[m][n][j];
        if (EPI == 0) {
          ((short*)out)[r * N + cg] = f2bf(v);
        } else if (EPI == 3) {
          ((float*)out)[r * N + cg] = ((const float*)aux)[r * N + cg] + v;
        } else if (EPI == 4) {
          float gv = bf2f(((const short*)aux)[r * N + cg]);
          float sg = gv / (1.0f + __expf(-gv));
          ((short*)out)[r * N + cg] = f2bf(sg * v);
        }
      }
    }
  }
}

// ---------------- causal flash attention -----------------------------------
__global__ __launch_bounds__(512) void attn_k(const short* __restrict__ Qh,
                                              const short* __restrict__ Kh,
                                              const short* __restrict__ Vt,
                                              short* __restrict__ Ob) {
  __shared__ short Qs[128 * 128];
  __shared__ short Ks[128 * 128];
  __shared__ short Vs[128 * 128];
  __shared__ short Ps[128 * 128];
  int qt = blockIdx.x, bh = blockIdx.y;
  int t = threadIdx.x, w = t >> 6, lane = t & 63, lg = lane >> 4, c = lane & 15;
  int q0 = qt << 7;
  const short* Qb = Qh + (long)bh * SS * HDD;
  const short* Kb = Kh + (long)bh * SS * HDD;
  const short* Vb = Vt + (long)bh * HDD * SS;
#pragma unroll
  for (int i = 0; i < 4; ++i) {
    int idx = i * 512 + t;
    int row = idx >> 4, p = idx & 15;
    int col = (p ^ (row & 7)) << 3;
    GLL16(Qb + (long)(q0 + row) * HDD + col, Qs + (i * 512 + w * 64) * 8);
  }
  __syncthreads();
  short8 qf[4];
  int qrow = w * 16 + c;
#pragma unroll
  for (int kk = 0; kk < 4; ++kk)
    qf[kk] = *(const short8*)(Qs + qrow * 128 + ((((kk << 2) | lg) ^ (qrow & 7)) << 3));

  f32x4 o[8] = {};
  float mrun[4] = {-1e30f, -1e30f, -1e30f, -1e30f};
  float lrun[4] = {0.f, 0.f, 0.f, 0.f};
  const float scale = 0.08838834764831845f;
  for (int kt = 0; kt <= qt; ++kt) {
    int kv0 = kt << 7;
    __syncthreads();
#pragma unroll
    for (int i = 0; i < 4; ++i) {
      int idx = i * 512 + t;
      int row = idx >> 4, p = idx & 15;
      int col = (p ^ (row & 7)) << 3;
      GLL16(Kb + (long)(kv0 + row) * HDD + col, Ks + (i * 512 + w * 64) * 8);
      GLL16(Vb + (long)row * SS + kv0 + col, Vs + (i * 512 + w * 64) * 8);
    }
    __syncthreads();
    f32x4 sv[8];
#pragma unroll
    for (int n = 0; n < 8; ++n) {
      f32x4 acc = {};
#pragma unroll
      for (int kk = 0; kk < 4; ++kk) {
        int krow = n * 16 + c;
        short8 kf = *(const short8*)(Ks + krow * 128 + ((((kk << 2) | lg) ^ (krow & 7)) << 3));
        acc = __builtin_amdgcn_mfma_f32_16x16x32_bf16(qf[kk], kf, acc, 0, 0, 0);
      }
      sv[n] = acc;
    }
    int qg = q0 + w * 16 + lg * 4;
    if (kt == qt) {
#pragma unroll
      for (int n = 0; n < 8; ++n) {
        int col = kv0 + n * 16 + c;
#pragma unroll
        for (int j = 0; j < 4; ++j) {
          float xv = sv[n][j] * scale;
          sv[n][j] = (col > qg + j) ? -1e30f : xv;
        }
      }
    } else {
#pragma unroll
      for (int n = 0; n < 8; ++n)
#pragma unroll
        for (int j = 0; j < 4; ++j) sv[n][j] *= scale;
    }
    float alpha[4];
#pragma unroll
    for (int j = 0; j < 4; ++j) {
      float mx = sv[0][j];
#pragma unroll
      for (int n = 1; n < 8; ++n) mx = fmaxf(mx, sv[n][j]);
      mx = fmaxf(mx, __shfl_xor(mx, 1));
      mx = fmaxf(mx, __shfl_xor(mx, 2));
      mx = fmaxf(mx, __shfl_xor(mx, 4));
      mx = fmaxf(mx, __shfl_xor(mx, 8));
      float mnew = fmaxf(mrun[j], mx);
      alpha[j] = __expf(mrun[j] - mnew);
      mrun[j] = mnew;
    }
    float rsum[4] = {0.f, 0.f, 0.f, 0.f};
#pragma unroll
    for (int n = 0; n < 8; ++n)
#pragma unroll
      for (int j = 0; j < 4; ++j) {
        float p = __expf(sv[n][j] - mrun[j]);
        sv[n][j] = p;
        rsum[j] += p;
      }
#pragma unroll
    for (int j = 0; j < 4; ++j) {
      rsum[j] += __shfl_xor(rsum[j], 1);
      rsum[j] += __shfl_xor(rsum[j], 2);
      rsum[j] += __shfl_xor(rsum[j], 4);
      rsum[j] += __shfl_xor(rsum[j], 8);
      lrun[j] = lrun[j] * alpha[j] + rsum[j];
    }
#pragma unroll
    for (int n = 0; n < 8; ++n)
#pragma unroll
      for (int j = 0; j < 4; ++j) o[n][j] *= alpha[j];
#pragma unroll
    for (int n = 0; n < 8; ++n)
#pragma unroll
      for (int j = 0; j < 4; ++j) {
        int row = w * 16 + lg * 4 + j;
        int slot = (2 * n + (c >> 3)) ^ (row & 7);
        Ps[row * 128 + slot * 8 + (c & 7)] = f2bf(sv[n][j]);
      }
    __syncthreads();
    short8 pf[4];
    int prow = w * 16 + c;
#pragma unroll
    for (int kk = 0; kk < 4; ++kk)
      pf[kk] = *(const short8*)(Ps + prow * 128 + ((((kk << 2) | lg) ^ (prow & 7)) << 3));
#pragma unroll
    for (int n = 0; n < 8; ++n) {
#pragma unroll
      for (int kk = 0; kk < 4; ++kk) {
        int vrow = n * 16 + c;
        short8 vf = *(const short8*)(Vs + vrow * 128 + ((((kk << 2) | lg) ^ (vrow & 7)) << 3));
        o[n] = __builtin_amdgcn_mfma_f32_16x16x32_bf16(pf[kk], vf, o[n], 0, 0, 0);
      }
    }
  }
  int head = bh & (NHH - 1), b = bh >> 4;
#pragma unroll
  for (int j = 0; j < 4; ++j) {
    float inv = 1.0f / lrun[j];
    int s = q0 + w * 16 + lg * 4 + j;
#pragma unroll
    for (int n = 0; n < 8; ++n) {
      int hcol = head * 128 + n * 16 + c;
      Ob[((long)(b * SS + s)) * HH + hcol] = f2bf(o[n][j] * inv);
    }
  }
}

// ---------------------------------------------------------------------------
extern "C" void kernel_launch(void* const* d_in, const int* in_sizes, int n_in,
                              void* d_out, int out_size, void* d_ws, size_t ws_size,
                              hipStream_t stream) {
  (void)in_sizes; (void)n_in; (void)out_size;
  const float* x     = (const float*)d_in[0];
  const float* wq    = (const float*)d_in[2];
  const float* wk    = (const float*)d_in[3];
  const float* wv    = (const float*)d_in[4];
  const float* wo    = (const float*)d_in[5];
  const float* wgt   = (const float*)d_in[6];
  const float* wup   = (const float*)d_in[7];
  const float* wdn   = (const float*)d_in[8];
  const float* gin   = (const float*)d_in[9];
  const float* gpost = (const float*)d_in[10];
  float* out = (float*)d_out;

  const size_t R0 = 0;
  const size_t R1 = (size_t)32 << 20;
  const size_t R2 = (size_t)48 << 20;
  const size_t R3 = (size_t)112 << 20;
  const size_t NEED = (size_t)176 << 20;
  if (ws_size < NEED) return;

  short* wtq = (short*)((char*)d_ws + R0);
  short* wtk = wtq + (size_t)HH * HH;
  short* wtv = wtk + (size_t)HH * HH;
  short* wto = wtv + (size_t)HH * HH;
  short* wtd = (short*)((char*)d_ws + R0);
  short* hb  = (short*)((char*)d_ws + R1);
  short* h2  = hb;
  short* qh  = (short*)((char*)d_ws + R2);
  short* kh  = qh + (size_t)MM * HH;
  short* vt  = kh + (size_t)MM * HH;
  short* ab  = vt + (size_t)MM * HH;
  short* wtg = (short*)((char*)d_ws + R2);
  short* wtu = wtg + (size_t)HH * FF;
  short* gateb = (short*)((char*)d_ws + R3);

  dim3 b256(256, 1, 1);
  transpose_cast<<<dim3(HH / 32, HH / 32), b256, 0, stream>>>(wq, wtq, HH, HH);
  transpose_cast<<<dim3(HH / 32, HH / 32), b256, 0, stream>>>(wk, wtk, HH, HH);
  transpose_cast<<<dim3(HH / 32, HH / 32), b256, 0, stream>>>(wv, wtv, HH, HH);
  transpose_cast<<<dim3(HH / 32, HH / 32), b256, 0, stream>>>(wo, wto, HH, HH);

  rmsnorm_k<<<dim3(MM), b256, 0, stream>>>(x, gin, hb);

  dim3 gH((MM / 128) * (HH / 128), 1, 1);  // 512 WGs
  gemm_bt<1><<<gH, b256, 0, stream>>>(hb, wtq, MM, HH, HH, qh, nullptr);
  gemm_bt<1><<<gH, b256, 0, stream>>>(hb, wtk, MM, HH, HH, kh, nullptr);
  gemm_bt<2><<<gH, b256, 0, stream>>>(hb, wtv, MM, HH, HH, vt, nullptr);

  attn_k<<<dim3(SS / 128, BB * NHH), dim3(512, 1, 1), 0, stream>>>(qh, kh, vt, ab);

  gemm_bt<3><<<gH, b256, 0, stream>>>(ab, wto, MM, HH, HH, out, x);

  transpose_cast<<<dim3(FF / 32, HH / 32), b256, 0, stream>>>(wgt, wtg, HH, FF);
  transpose_cast<<<dim3(FF / 32, HH / 32), b256, 0, stream>>>(wup, wtu, HH, FF);
  transpose_cast<<<dim3(HH / 32, FF / 32), b256, 0, stream>>>(wdn, wtd, FF, HH);

  rmsnorm_k<<<dim3(MM), b256, 0, stream>>>(out, gpost, h2);

  dim3 b512(512, 1, 1);
  dim3 gF256((MM / 256) * (FF / 256), 1, 1);  // 512 WGs
  gemm256<0><<<gF256, b512, 0, stream>>>(h2, wtg, MM, FF, HH, gateb, nullptr);
  gemm256<4><<<gF256, b512, 0, stream>>>(h2, wtu, MM, FF, HH, gateb, gateb);
  // down: gemm_bt keeps all 256 CUs busy (512 WGs vs gemm256's 128)
  gemm_bt<3><<<gH, b256, 0, stream>>>(gateb, wtd, MM, HH, FF, out, out);
}

// Round 6
// 1025.965 us; speedup vs baseline: 1.0177x; 1.0177x over previous
//
#include <hip/hip_runtime.h>

// Decoder layer: x -> rms -> QKV -> causal attn -> +x@wo -> rms -> SwiGLU -> +down
// B=2 S=2048 H=2048 NH=16 HD=128 FF=8192, fp32 I/O, bf16 MFMA compute.

#define HH 2048
#define FF 8192
#define BB 2
#define SS 2048
#define NHH 16
#define HDD 128
#define MM (BB * SS)  // 4096 rows

typedef __attribute__((ext_vector_type(8))) short short8;
typedef __attribute__((ext_vector_type(4))) short short4v;
typedef __attribute__((ext_vector_type(4))) float f32x4;

#define DEV __device__ __forceinline__

DEV short f2bf(float f) {  // RNE f32->bf16
  unsigned u = __builtin_bit_cast(unsigned, f);
  u += 0x7fffu + ((u >> 16) & 1u);
  return (short)(u >> 16);
}
DEV float bf2f(short s) {
  unsigned u = ((unsigned)(unsigned short)s) << 16;
  return __builtin_bit_cast(float, u);
}

// async global->LDS, 16B per lane; lds ptr must be wave-uniform, HW adds lane*16
#define GLL16(gp, lp)                                                    \
  __builtin_amdgcn_global_load_lds(                                      \
      (const __attribute__((address_space(1))) void*)(gp),               \
      (__attribute__((address_space(3))) void*)(lp), 16, 0, 0)

// ---------------- weight transpose + cast: W[K][N] f32 -> Wt[N][K] bf16 -----
__global__ __launch_bounds__(256) void transpose_cast(
    const float* __restrict__ W, short* __restrict__ Wt, int K, int N) {
  __shared__ float tile[32][33];
  int n0 = blockIdx.x * 32, k0 = blockIdx.y * 32;
  int tx = threadIdx.x & 31, ty = threadIdx.x >> 5;
#pragma unroll
  for (int i = 0; i < 32; i += 8)
    tile[ty + i][tx] = W[(long)(k0 + ty + i) * N + n0 + tx];
  __syncthreads();
#pragma unroll
  for (int i = 0; i < 32; i += 8)
    Wt[(long)(n0 + ty + i) * K + k0 + tx] = f2bf(tile[tx][ty + i]);
}

// ---------------- RMSNorm row kernel: f32 in -> bf16 out --------------------
__global__ __launch_bounds__(256) void rmsnorm_k(const float* __restrict__ x,
                                                 const float* __restrict__ g,
                                                 short* __restrict__ out) {
  int row = blockIdx.x;
  int t = threadIdx.x;
  const float* xr = x + (long)row * HH;
  f32x4 v0 = *(const f32x4*)(xr + t * 4);
  f32x4 v1 = *(const f32x4*)(xr + 1024 + t * 4);
  float ss = v0[0] * v0[0] + v0[1] * v0[1] + v0[2] * v0[2] + v0[3] * v0[3] +
             v1[0] * v1[0] + v1[1] * v1[1] + v1[2] * v1[2] + v1[3] * v1[3];
#pragma unroll
  for (int off = 1; off < 64; off <<= 1) ss += __shfl_xor(ss, off);
  __shared__ float red[4];
  if ((t & 63) == 0) red[t >> 6] = ss;
  __syncthreads();
  float tot = red[0] + red[1] + red[2] + red[3];
  float rs = rsqrtf(tot * (1.0f / HH) + 1e-6f);
  f32x4 g0 = *(const f32x4*)(g + t * 4);
  f32x4 g1 = *(const f32x4*)(g + 1024 + t * 4);
  short4v o0, o1;
#pragma unroll
  for (int e = 0; e < 4; ++e) {
    o0[e] = f2bf(v0[e] * rs * g0[e]);
    o1[e] = f2bf(v1[e] * rs * g1[e]);
  }
  *(short4v*)(out + (long)row * HH + t * 4) = o0;
  *(short4v*)(out + (long)row * HH + 1024 + t * 4) = o1;
}

// ---------------- bf16 MFMA GEMM (m97 128x128, 2-phase) ---------------------
// EPI: 0 plain bf16 [M][N]; 1 bf16 per-head [b,h,s,d]; 2 bf16 Vt [b,h,d,s];
//      3 f32 out = aux(f32)[M][N] + acc; 4 bf16 out = silu(aux bf16)*acc;
//      5 QKV concat (N=6144): out base -> qh | kh | vt regions.
template <int EPI>
__global__ __launch_bounds__(256) void gemm_bt(const short* __restrict__ A,
                                               const short* __restrict__ Bt,
                                               int M, int N, int K,
                                               void* out, const void* aux) {
  __shared__ short As[128 * 64];
  __shared__ short Bs[128 * 64];
  int nbn = N >> 7;
  int nwg = gridDim.x;
  int bid = blockIdx.x;
  int qq = nwg >> 3, rr = nwg & 7;
  int xcd = bid & 7, lid = bid >> 3;
  int wg = (xcd < rr ? xcd * (qq + 1) : rr * (qq + 1) + (xcd - rr) * qq) + lid;
  int bm = wg / nbn, bn = wg % nbn;
  int t = threadIdx.x, w = t >> 6, lane = t & 63, lg = lane >> 4, c = lane & 15;
  int wr = w >> 1, wc = w & 1;
  const short* Abase = A + (long)bm * 128 * K;
  const short* Bbase = Bt + (long)bn * 128 * K;
  f32x4 acc[4][4] = {};
  int nk = K >> 6;
  for (int kt = 0; kt < nk; ++kt) {
    int k0 = kt << 6;
    __syncthreads();
#pragma unroll
    for (int i = 0; i < 4; ++i) {
      int idx = i * 256 + t;
      int row = idx >> 3, p = idx & 7;
      int col = k0 + ((p ^ (row & 7)) << 3);
      GLL16(Abase + (long)row * K + col, As + (i * 256 + w * 64) * 8);
      GLL16(Bbase + (long)row * K + col, Bs + (i * 256 + w * 64) * 8);
    }
    __syncthreads();
#pragma unroll
    for (int kk = 0; kk < 2; ++kk) {
      short8 af[4], bfr[4];
#pragma unroll
      for (int m = 0; m < 4; ++m) {
        int row = wr * 64 + m * 16 + c;
        af[m] = *(const short8*)(As + row * 64 + ((((kk << 2) | lg) ^ (row & 7)) << 3));
      }
#pragma unroll
      for (int n = 0; n < 4; ++n) {
        int row = wc * 64 + n * 16 + c;
        bfr[n] = *(const short8*)(Bs + row * 64 + ((((kk << 2) | lg) ^ (row & 7)) << 3));
      }
#pragma unroll
      for (int m = 0; m < 4; ++m)
#pragma unroll
        for (int n = 0; n < 4; ++n)
          acc[m][n] = __builtin_amdgcn_mfma_f32_16x16x32_bf16(af[m], bfr[n], acc[m][n], 0, 0, 0);
    }
  }
#pragma unroll
  for (int m = 0; m < 4; ++m) {
#pragma unroll
    for (int n = 0; n < 4; ++n) {
      int rL = wr * 64 + m * 16 + lg * 4;
      int cL = wc * 64 + n * 16 + c;
      long rg = (long)bm * 128 + rL;
      long cg = (long)bn * 128 + cL;
      if (EPI == 2) {
        int b = (int)(rg >> 11), s = (int)(rg & 2047);
        int head = (int)(cg >> 7), d = (int)(cg & 127);
        short4v pk;
#pragma unroll
        for (int j = 0; j < 4; ++j) pk[j] = f2bf(acc[m][n][j]);
        *(short4v*)((short*)out + ((long)(b * NHH + head) * HDD + d) * SS + s) = pk;
      } else if (EPI == 5) {
        short* base = (short*)out;
        int mat = (int)(cg >> 11);         // 0=q, 1=k, 2=v (uniform per block)
        int cc = (int)(cg & 2047);
        int head = cc >> 7, d = cc & 127;
        if (mat == 2) {                    // vt[b*NH+h][d][s], packed 4 s
          int b = (int)(rg >> 11), s = (int)(rg & 2047);
          short4v pk;
#pragma unroll
          for (int j = 0; j < 4; ++j) pk[j] = f2bf(acc[m][n][j]);
          *(short4v*)(base + (size_t)2 * MM * HH +
                      ((long)(b * NHH + head) * HDD + d) * SS + s) = pk;
        } else {                           // q/k: [b*NH+h][s][d]
          short* dst = base + (size_t)mat * MM * HH;
#pragma unroll
          for (int j = 0; j < 4; ++j) {
            long r = rg + j;
            int b = (int)(r >> 11), s = (int)(r & 2047);
            dst[((long)(b * NHH + head) * SS + s) * HDD + d] = f2bf(acc[m][n][j]);
          }
        }
      } else {
#pragma unroll
        for (int j = 0; j < 4; ++j) {
          long r = rg + j;
          float v = acc[m][n][j];
          if (EPI == 0) {
            ((short*)out)[r * N + cg] = f2bf(v);
          } else if (EPI == 1) {
            int b = (int)(r >> 11), s = (int)(r & 2047);
            int head = (int)(cg >> 7), d = (int)(cg & 127);
            ((short*)out)[((long)(b * NHH + head) * SS + s) * HDD + d] = f2bf(v);
          } else if (EPI == 3) {
            ((float*)out)[r * N + cg] = ((const float*)aux)[r * N + cg] + v;
          } else if (EPI == 4) {
            float gv = bf2f(((const short*)aux)[r * N + cg]);
            float sg = gv / (1.0f + __expf(-gv));
            ((short*)out)[r * N + cg] = f2bf(sg * v);
          }
        }
      }
    }
  }
}

// ---------------- fused gate+up GLU GEMM ------------------------------------
// out[M][N] = bf16( silu(A@Bg^T) * (A@Bu^T) ). Same m97 structure as gemm_bt
// but stages A once for BOTH B-tiles: 2x MFMA per ~1.5x staging/VALU, and no
// gate intermediate round-trip (saves 128 MB HBM).
__global__ __launch_bounds__(256) void gemm_glu(const short* __restrict__ A,
                                                const short* __restrict__ Bg,
                                                const short* __restrict__ Bu,
                                                int M, int N, int K,
                                                short* __restrict__ out) {
  __shared__ short As[128 * 64];
  __shared__ short Gs[128 * 64];
  __shared__ short Us[128 * 64];
  int nbn = N >> 7;
  int nwg = gridDim.x;
  int bid = blockIdx.x;
  int qq = nwg >> 3, rr = nwg & 7;
  int xcd = bid & 7, lid = bid >> 3;
  int wg = (xcd < rr ? xcd * (qq + 1) : rr * (qq + 1) + (xcd - rr) * qq) + lid;
  int bm = wg / nbn, bn = wg % nbn;
  int t = threadIdx.x, w = t >> 6, lane = t & 63, lg = lane >> 4, c = lane & 15;
  int wr = w >> 1, wc = w & 1;
  const short* Ab = A + (long)bm * 128 * K;
  const short* Gb = Bg + (long)bn * 128 * K;
  const short* Ub = Bu + (long)bn * 128 * K;
  // loop-invariant stage source pointers
  const short* pA[4];
  const short* pG[4];
  const short* pU[4];
#pragma unroll
  for (int i = 0; i < 4; ++i) {
    int idx = i * 256 + t;
    int row = idx >> 3, p = idx & 7;
    long off = (long)row * K + ((p ^ (row & 7)) << 3);
    pA[i] = Ab + off;
    pG[i] = Gb + off;
    pU[i] = Ub + off;
  }
  f32x4 ag[4][4] = {}, au[4][4] = {};
  int nk = K >> 6;
  for (int kt = 0; kt < nk; ++kt) {
    int k0 = kt << 6;
    __syncthreads();
#pragma unroll
    for (int i = 0; i < 4; ++i) {
      GLL16(pA[i] + k0, As + (i * 256 + w * 64) * 8);
      GLL16(pG[i] + k0, Gs + (i * 256 + w * 64) * 8);
      GLL16(pU[i] + k0, Us + (i * 256 + w * 64) * 8);
    }
    __syncthreads();
#pragma unroll
    for (int kk = 0; kk < 2; ++kk) {
      short8 af[4], gf[4], uf[4];
#pragma unroll
      for (int m = 0; m < 4; ++m) {
        int row = wr * 64 + m * 16 + c;
        af[m] = *(const short8*)(As + row * 64 + ((((kk << 2) | lg) ^ (row & 7)) << 3));
      }
#pragma unroll
      for (int n = 0; n < 4; ++n) {
        int row = wc * 64 + n * 16 + c;
        int o = row * 64 + ((((kk << 2) | lg) ^ (row & 7)) << 3);
        gf[n] = *(const short8*)(Gs + o);
        uf[n] = *(const short8*)(Us + o);
      }
#pragma unroll
      for (int m = 0; m < 4; ++m)
#pragma unroll
        for (int n = 0; n < 4; ++n) {
          ag[m][n] = __builtin_amdgcn_mfma_f32_16x16x32_bf16(af[m], gf[n], ag[m][n], 0, 0, 0);
          au[m][n] = __builtin_amdgcn_mfma_f32_16x16x32_bf16(af[m], uf[n], au[m][n], 0, 0, 0);
        }
    }
  }
#pragma unroll
  for (int m = 0; m < 4; ++m) {
#pragma unroll
    for (int n = 0; n < 4; ++n) {
      int rL = wr * 64 + m * 16 + lg * 4;
      int cL = wc * 64 + n * 16 + c;
      long cg = (long)bn * 128 + cL;
#pragma unroll
      for (int j = 0; j < 4; ++j) {
        long r = (long)bm * 128 + rL + j;
        float g = ag[m][n][j];
        float u = au[m][n][j];
        float sg = g / (1.0f + __expf(-g));
        out[r * N + cg] = f2bf(sg * u);
      }
    }
  }
}

// ---------------- causal flash attention -----------------------------------
__global__ __launch_bounds__(512) void attn_k(const short* __restrict__ Qh,
                                              const short* __restrict__ Kh,
                                              const short* __restrict__ Vt,
                                              short* __restrict__ Ob) {
  __shared__ short Qs[128 * 128];
  __shared__ short Ks[128 * 128];
  __shared__ short Vs[128 * 128];
  __shared__ short Ps[128 * 128];
  int qt = blockIdx.x, bh = blockIdx.y;
  int t = threadIdx.x, w = t >> 6, lane = t & 63, lg = lane >> 4, c = lane & 15;
  int q0 = qt << 7;
  const short* Qb = Qh + (long)bh * SS * HDD;
  const short* Kb = Kh + (long)bh * SS * HDD;
  const short* Vb = Vt + (long)bh * HDD * SS;
#pragma unroll
  for (int i = 0; i < 4; ++i) {
    int idx = i * 512 + t;
    int row = idx >> 4, p = idx & 15;
    int col = (p ^ (row & 7)) << 3;
    GLL16(Qb + (long)(q0 + row) * HDD + col, Qs + (i * 512 + w * 64) * 8);
  }
  __syncthreads();
  short8 qf[4];
  int qrow = w * 16 + c;
#pragma unroll
  for (int kk = 0; kk < 4; ++kk)
    qf[kk] = *(const short8*)(Qs + qrow * 128 + ((((kk << 2) | lg) ^ (qrow & 7)) << 3));

  f32x4 o[8] = {};
  float mrun[4] = {-1e30f, -1e30f, -1e30f, -1e30f};
  float lrun[4] = {0.f, 0.f, 0.f, 0.f};
  const float scale = 0.08838834764831845f;
  for (int kt = 0; kt <= qt; ++kt) {
    int kv0 = kt << 7;
    __syncthreads();
#pragma unroll
    for (int i = 0; i < 4; ++i) {
      int idx = i * 512 + t;
      int row = idx >> 4, p = idx & 15;
      int col = (p ^ (row & 7)) << 3;
      GLL16(Kb + (long)(kv0 + row) * HDD + col, Ks + (i * 512 + w * 64) * 8);
      GLL16(Vb + (long)row * SS + kv0 + col, Vs + (i * 512 + w * 64) * 8);
    }
    __syncthreads();
    f32x4 sv[8];
#pragma unroll
    for (int n = 0; n < 8; ++n) {
      f32x4 acc = {};
#pragma unroll
      for (int kk = 0; kk < 4; ++kk) {
        int krow = n * 16 + c;
        short8 kf = *(const short8*)(Ks + krow * 128 + ((((kk << 2) | lg) ^ (krow & 7)) << 3));
        acc = __builtin_amdgcn_mfma_f32_16x16x32_bf16(qf[kk], kf, acc, 0, 0, 0);
      }
      sv[n] = acc;
    }
    int qg = q0 + w * 16 + lg * 4;
    if (kt == qt) {
#pragma unroll
      for (int n = 0; n < 8; ++n) {
        int col = kv0 + n * 16 + c;
#pragma unroll
        for (int j = 0; j < 4; ++j) {
          float xv = sv[n][j] * scale;
          sv[n][j] = (col > qg + j) ? -1e30f : xv;
        }
      }
    } else {
#pragma unroll
      for (int n = 0; n < 8; ++n)
#pragma unroll
        for (int j = 0; j < 4; ++j) sv[n][j] *= scale;
    }
    float alpha[4];
#pragma unroll
    for (int j = 0; j < 4; ++j) {
      float mx = sv[0][j];
#pragma unroll
      for (int n = 1; n < 8; ++n) mx = fmaxf(mx, sv[n][j]);
      mx = fmaxf(mx, __shfl_xor(mx, 1));
      mx = fmaxf(mx, __shfl_xor(mx, 2));
      mx = fmaxf(mx, __shfl_xor(mx, 4));
      mx = fmaxf(mx, __shfl_xor(mx, 8));
      float mnew = fmaxf(mrun[j], mx);
      alpha[j] = __expf(mrun[j] - mnew);
      mrun[j] = mnew;
    }
    float rsum[4] = {0.f, 0.f, 0.f, 0.f};
#pragma unroll
    for (int n = 0; n < 8; ++n)
#pragma unroll
      for (int j = 0; j < 4; ++j) {
        float p = __expf(sv[n][j] - mrun[j]);
        sv[n][j] = p;
        rsum[j] += p;
      }
#pragma unroll
    for (int j = 0; j < 4; ++j) {
      rsum[j] += __shfl_xor(rsum[j], 1);
      rsum[j] += __shfl_xor(rsum[j], 2);
      rsum[j] += __shfl_xor(rsum[j], 4);
      rsum[j] += __shfl_xor(rsum[j], 8);
      lrun[j] = lrun[j] * alpha[j] + rsum[j];
    }
#pragma unroll
    for (int n = 0; n < 8; ++n)
#pragma unroll
      for (int j = 0; j < 4; ++j) o[n][j] *= alpha[j];
#pragma unroll
    for (int n = 0; n < 8; ++n)
#pragma unroll
      for (int j = 0; j < 4; ++j) {
        int row = w * 16 + lg * 4 + j;
        int slot = (2 * n + (c >> 3)) ^ (row & 7);
        Ps[row * 128 + slot * 8 + (c & 7)] = f2bf(sv[n][j]);
      }
    __syncthreads();
    short8 pf[4];
    int prow = w * 16 + c;
#pragma unroll
    for (int kk = 0; kk < 4; ++kk)
      pf[kk] = *(const short8*)(Ps + prow * 128 + ((((kk << 2) | lg) ^ (prow & 7)) << 3));
#pragma unroll
    for (int n = 0; n < 8; ++n) {
#pragma unroll
      for (int kk = 0; kk < 4; ++kk) {
        int vrow = n * 16 + c;
        short8 vf = *(const short8*)(Vs + vrow * 128 + ((((kk << 2) | lg) ^ (vrow & 7)) << 3));
        o[n] = __builtin_amdgcn_mfma_f32_16x16x32_bf16(pf[kk], vf, o[n], 0, 0, 0);
      }
    }
  }
  int head = bh & (NHH - 1), b = bh >> 4;
#pragma unroll
  for (int j = 0; j < 4; ++j) {
    float inv = 1.0f / lrun[j];
    int s = q0 + w * 16 + lg * 4 + j;
#pragma unroll
    for (int n = 0; n < 8; ++n) {
      int hcol = head * 128 + n * 16 + c;
      Ob[((long)(b * SS + s)) * HH + hcol] = f2bf(o[n][j] * inv);
    }
  }
}

// ---------------------------------------------------------------------------
extern "C" void kernel_launch(void* const* d_in, const int* in_sizes, int n_in,
                              void* d_out, int out_size, void* d_ws, size_t ws_size,
                              hipStream_t stream) {
  (void)in_sizes; (void)n_in; (void)out_size;
  const float* x     = (const float*)d_in[0];
  const float* wq    = (const float*)d_in[2];
  const float* wk    = (const float*)d_in[3];
  const float* wv    = (const float*)d_in[4];
  const float* wo    = (const float*)d_in[5];
  const float* wgt   = (const float*)d_in[6];
  const float* wup   = (const float*)d_in[7];
  const float* wdn   = (const float*)d_in[8];
  const float* gin   = (const float*)d_in[9];
  const float* gpost = (const float*)d_in[10];
  float* out = (float*)d_out;

  const size_t R0 = 0;
  const size_t R1 = (size_t)32 << 20;
  const size_t R2 = (size_t)48 << 20;
  const size_t R3 = (size_t)112 << 20;
  const size_t NEED = (size_t)176 << 20;
  if (ws_size < NEED) return;

  short* wtq = (short*)((char*)d_ws + R0);  // wtq|wtk|wtv contiguous = QKV concat
  short* wtk = wtq + (size_t)HH * HH;
  short* wtv = wtk + (size_t)HH * HH;
  short* wto = wtv + (size_t)HH * HH;
  short* wtd = (short*)((char*)d_ws + R0);
  short* hb  = (short*)((char*)d_ws + R1);
  short* h2  = hb;
  short* qh  = (short*)((char*)d_ws + R2);  // qh|kh|vt|ab
  short* kh  = qh + (size_t)MM * HH;
  short* vt  = kh + (size_t)MM * HH;
  short* ab  = vt + (size_t)MM * HH;
  short* wtg = (short*)((char*)d_ws + R2);
  short* wtu = wtg + (size_t)HH * FF;
  short* gateb = (short*)((char*)d_ws + R3);

  dim3 b256(256, 1, 1);
  transpose_cast<<<dim3(HH / 32, HH / 32), b256, 0, stream>>>(wq, wtq, HH, HH);
  transpose_cast<<<dim3(HH / 32, HH / 32), b256, 0, stream>>>(wk, wtk, HH, HH);
  transpose_cast<<<dim3(HH / 32, HH / 32), b256, 0, stream>>>(wv, wtv, HH, HH);
  transpose_cast<<<dim3(HH / 32, HH / 32), b256, 0, stream>>>(wo, wto, HH, HH);

  rmsnorm_k<<<dim3(MM), b256, 0, stream>>>(x, gin, hb);

  // fused QKV: N=6144 over contiguous wtq|wtk|wtv; epilogue routes per block
  dim3 gQKV((MM / 128) * (3 * HH / 128), 1, 1);  // 1536 WGs
  gemm_bt<5><<<gQKV, b256, 0, stream>>>(hb, wtq, MM, 3 * HH, HH, qh, nullptr);

  attn_k<<<dim3(SS / 128, BB * NHH), dim3(512, 1, 1), 0, stream>>>(qh, kh, vt, ab);

  dim3 gH((MM / 128) * (HH / 128), 1, 1);  // 512 WGs
  gemm_bt<3><<<gH, b256, 0, stream>>>(ab, wto, MM, HH, HH, out, x);

  transpose_cast<<<dim3(FF / 32, HH / 32), b256, 0, stream>>>(wgt, wtg, HH, FF);
  transpose_cast<<<dim3(FF / 32, HH / 32), b256, 0, stream>>>(wup, wtu, HH, FF);
  transpose_cast<<<dim3(HH / 32, FF / 32), b256, 0, stream>>>(wdn, wtd, FF, HH);

  rmsnorm_k<<<dim3(MM), b256, 0, stream>>>(out, gpost, h2);

  // fused gate+up: one pass, silu applied on f32 accumulators
  dim3 gF((MM / 128) * (FF / 128), 1, 1);  // 2048 WGs
  gemm_glu<<<gF, b256, 0, stream>>>(h2, wtg, wtu, MM, FF, HH, gateb);

  // down + residual (in-place on d_out)
  gemm_bt<3><<<gH, b256, 0, stream>>>(gateb, wtd, MM, HH, FF, out, out);
}

// Round 7
// 914.184 us; speedup vs baseline: 1.1422x; 1.1223x over previous
//
#include <hip/hip_runtime.h>

// Decoder layer: x -> rms -> QKV -> causal attn -> +x@wo -> rms -> SwiGLU -> +down
// B=2 S=2048 H=2048 NH=16 HD=128 FF=8192, fp32 I/O, bf16 MFMA compute.

#define HH 2048
#define FF 8192
#define BB 2
#define SS 2048
#define NHH 16
#define HDD 128
#define MM (BB * SS)  // 4096 rows

typedef __attribute__((ext_vector_type(8))) short short8;
typedef __attribute__((ext_vector_type(4))) short short4v;
typedef __attribute__((ext_vector_type(4))) float f32x4;

#define DEV __device__ __forceinline__

DEV short f2bf(float f) {  // RNE f32->bf16
  unsigned u = __builtin_bit_cast(unsigned, f);
  u += 0x7fffu + ((u >> 16) & 1u);
  return (short)(u >> 16);
}
DEV float bf2f(short s) {
  unsigned u = ((unsigned)(unsigned short)s) << 16;
  return __builtin_bit_cast(float, u);
}

// async global->LDS, 16B per lane; lds ptr must be wave-uniform, HW adds lane*16
#define GLL16(gp, lp)                                                    \
  __builtin_amdgcn_global_load_lds(                                      \
      (const __attribute__((address_space(1))) void*)(gp),               \
      (__attribute__((address_space(3))) void*)(lp), 16, 0, 0)

// ---------------- weight transpose + cast: W[K][N] f32 -> Wt[N][K] bf16 -----
__global__ __launch_bounds__(256) void transpose_cast(
    const float* __restrict__ W, short* __restrict__ Wt, int K, int N) {
  __shared__ float tile[32][33];
  int n0 = blockIdx.x * 32, k0 = blockIdx.y * 32;
  int tx = threadIdx.x & 31, ty = threadIdx.x >> 5;
#pragma unroll
  for (int i = 0; i < 32; i += 8)
    tile[ty + i][tx] = W[(long)(k0 + ty + i) * N + n0 + tx];
  __syncthreads();
#pragma unroll
  for (int i = 0; i < 32; i += 8)
    Wt[(long)(n0 + ty + i) * K + k0 + tx] = f2bf(tile[tx][ty + i]);
}

// ---------------- RMSNorm row kernel: f32 in -> bf16 out --------------------
__global__ __launch_bounds__(256) void rmsnorm_k(const float* __restrict__ x,
                                                 const float* __restrict__ g,
                                                 short* __restrict__ out) {
  int row = blockIdx.x;
  int t = threadIdx.x;
  const float* xr = x + (long)row * HH;
  f32x4 v0 = *(const f32x4*)(xr + t * 4);
  f32x4 v1 = *(const f32x4*)(xr + 1024 + t * 4);
  float ss = v0[0] * v0[0] + v0[1] * v0[1] + v0[2] * v0[2] + v0[3] * v0[3] +
             v1[0] * v1[0] + v1[1] * v1[1] + v1[2] * v1[2] + v1[3] * v1[3];
#pragma unroll
  for (int off = 1; off < 64; off <<= 1) ss += __shfl_xor(ss, off);
  __shared__ float red[4];
  if ((t & 63) == 0) red[t >> 6] = ss;
  __syncthreads();
  float tot = red[0] + red[1] + red[2] + red[3];
  float rs = rsqrtf(tot * (1.0f / HH) + 1e-6f);
  f32x4 g0 = *(const f32x4*)(g + t * 4);
  f32x4 g1 = *(const f32x4*)(g + 1024 + t * 4);
  short4v o0, o1;
#pragma unroll
  for (int e = 0; e < 4; ++e) {
    o0[e] = f2bf(v0[e] * rs * g0[e]);
    o1[e] = f2bf(v1[e] * rs * g1[e]);
  }
  *(short4v*)(out + (long)row * HH + t * 4) = o0;
  *(short4v*)(out + (long)row * HH + 1024 + t * 4) = o1;
}

// ---------------- bf16 MFMA GEMM (m97 128x128, 2-phase) ---------------------
// Block mapping: bijective XCD swizzle (contiguous wg chunk per XCD), then
// GM=16 grouped supertile: each 256-wg chunk = 16bm x 16bn square, so the
// per-K-step active LDS-staging set is ~512 KB << 4 MB per-XCD L2
// (vs 4 MB with bm-major sweep = thrash -> 453 MB FETCH, R6 evidence).
// EPI: 0 plain bf16 [M][N]; 1 bf16 per-head [b,h,s,d]; 2 bf16 Vt [b,h,d,s];
//      3 f32 out = aux(f32)[M][N] + acc; 4 bf16 out = silu(aux bf16)*acc;
//      5 QKV concat (N=6144): out base -> qh | kh | vt regions.
template <int EPI>
__global__ __launch_bounds__(256) void gemm_bt(const short* __restrict__ A,
                                               const short* __restrict__ Bt,
                                               int M, int N, int K,
                                               void* out, const void* aux) {
  __shared__ short As[128 * 64];
  __shared__ short Bs[128 * 64];
  int nbn = N >> 7;
  int nwg = gridDim.x;
  int bid = blockIdx.x;
  // bijective XCD swizzle (m204)
  int qq = nwg >> 3, rr = nwg & 7;
  int xcd = bid & 7, lid = bid >> 3;
  int wg = (xcd < rr ? xcd * (qq + 1) : rr * (qq + 1) + (xcd - rr) * qq) + lid;
  // GM-grouped supertile mapping (requires (M/128) % 16 == 0; M=4096 -> 32)
  const int GM = 16;
  int gsz = GM * nbn;
  int gid = wg / gsz, rem = wg % gsz;
  int bm = gid * GM + (rem % GM);
  int bn = rem / GM;
  int t = threadIdx.x, w = t >> 6, lane = t & 63, lg = lane >> 4, c = lane & 15;
  int wr = w >> 1, wc = w & 1;
  const short* Abase = A + (long)bm * 128 * K;
  const short* Bbase = Bt + (long)bn * 128 * K;
  f32x4 acc[4][4] = {};
  int nk = K >> 6;
  for (int kt = 0; kt < nk; ++kt) {
    int k0 = kt << 6;
    __syncthreads();
#pragma unroll
    for (int i = 0; i < 4; ++i) {
      int idx = i * 256 + t;
      int row = idx >> 3, p = idx & 7;
      int col = k0 + ((p ^ (row & 7)) << 3);
      GLL16(Abase + (long)row * K + col, As + (i * 256 + w * 64) * 8);
      GLL16(Bbase + (long)row * K + col, Bs + (i * 256 + w * 64) * 8);
    }
    __syncthreads();
#pragma unroll
    for (int kk = 0; kk < 2; ++kk) {
      short8 af[4], bfr[4];
#pragma unroll
      for (int m = 0; m < 4; ++m) {
        int row = wr * 64 + m * 16 + c;
        af[m] = *(const short8*)(As + row * 64 + ((((kk << 2) | lg) ^ (row & 7)) << 3));
      }
#pragma unroll
      for (int n = 0; n < 4; ++n) {
        int row = wc * 64 + n * 16 + c;
        bfr[n] = *(const short8*)(Bs + row * 64 + ((((kk << 2) | lg) ^ (row & 7)) << 3));
      }
#pragma unroll
      for (int m = 0; m < 4; ++m)
#pragma unroll
        for (int n = 0; n < 4; ++n)
          acc[m][n] = __builtin_amdgcn_mfma_f32_16x16x32_bf16(af[m], bfr[n], acc[m][n], 0, 0, 0);
    }
  }
#pragma unroll
  for (int m = 0; m < 4; ++m) {
#pragma unroll
    for (int n = 0; n < 4; ++n) {
      int rL = wr * 64 + m * 16 + lg * 4;
      int cL = wc * 64 + n * 16 + c;
      long rg = (long)bm * 128 + rL;
      long cg = (long)bn * 128 + cL;
      if (EPI == 2) {
        int b = (int)(rg >> 11), s = (int)(rg & 2047);
        int head = (int)(cg >> 7), d = (int)(cg & 127);
        short4v pk;
#pragma unroll
        for (int j = 0; j < 4; ++j) pk[j] = f2bf(acc[m][n][j]);
        *(short4v*)((short*)out + ((long)(b * NHH + head) * HDD + d) * SS + s) = pk;
      } else if (EPI == 5) {
        short* base = (short*)out;
        int mat = (int)(cg >> 11);         // 0=q, 1=k, 2=v (uniform per block)
        int cc = (int)(cg & 2047);
        int head = cc >> 7, d = cc & 127;
        if (mat == 2) {                    // vt[b*NH+h][d][s], packed 4 s
          int b = (int)(rg >> 11), s = (int)(rg & 2047);
          short4v pk;
#pragma unroll
          for (int j = 0; j < 4; ++j) pk[j] = f2bf(acc[m][n][j]);
          *(short4v*)(base + (size_t)2 * MM * HH +
                      ((long)(b * NHH + head) * HDD + d) * SS + s) = pk;
        } else {                           // q/k: [b*NH+h][s][d]
          short* dst = base + (size_t)mat * MM * HH;
#pragma unroll
          for (int j = 0; j < 4; ++j) {
            long r = rg + j;
            int b = (int)(r >> 11), s = (int)(r & 2047);
            dst[((long)(b * NHH + head) * SS + s) * HDD + d] = f2bf(acc[m][n][j]);
          }
        }
      } else {
#pragma unroll
        for (int j = 0; j < 4; ++j) {
          long r = rg + j;
          float v = acc[m][n][j];
          if (EPI == 0) {
            ((short*)out)[r * N + cg] = f2bf(v);
          } else if (EPI == 1) {
            int b = (int)(r >> 11), s = (int)(r & 2047);
            int head = (int)(cg >> 7), d = (int)(cg & 127);
            ((short*)out)[((long)(b * NHH + head) * SS + s) * HDD + d] = f2bf(v);
          } else if (EPI == 3) {
            ((float*)out)[r * N + cg] = ((const float*)aux)[r * N + cg] + v;
          } else if (EPI == 4) {
            float gv = bf2f(((const short*)aux)[r * N + cg]);
            float sg = gv / (1.0f + __expf(-gv));
            ((short*)out)[r * N + cg] = f2bf(sg * v);
          }
        }
      }
    }
  }
}

// ---------------- causal flash attention -----------------------------------
__global__ __launch_bounds__(512) void attn_k(const short* __restrict__ Qh,
                                              const short* __restrict__ Kh,
                                              const short* __restrict__ Vt,
                                              short* __restrict__ Ob) {
  __shared__ short Qs[128 * 128];
  __shared__ short Ks[128 * 128];
  __shared__ short Vs[128 * 128];
  __shared__ short Ps[128 * 128];
  int qt = blockIdx.x, bh = blockIdx.y;
  int t = threadIdx.x, w = t >> 6, lane = t & 63, lg = lane >> 4, c = lane & 15;
  int q0 = qt << 7;
  const short* Qb = Qh + (long)bh * SS * HDD;
  const short* Kb = Kh + (long)bh * SS * HDD;
  const short* Vb = Vt + (long)bh * HDD * SS;
#pragma unroll
  for (int i = 0; i < 4; ++i) {
    int idx = i * 512 + t;
    int row = idx >> 4, p = idx & 15;
    int col = (p ^ (row & 7)) << 3;
    GLL16(Qb + (long)(q0 + row) * HDD + col, Qs + (i * 512 + w * 64) * 8);
  }
  __syncthreads();
  short8 qf[4];
  int qrow = w * 16 + c;
#pragma unroll
  for (int kk = 0; kk < 4; ++kk)
    qf[kk] = *(const short8*)(Qs + qrow * 128 + ((((kk << 2) | lg) ^ (qrow & 7)) << 3));

  f32x4 o[8] = {};
  float mrun[4] = {-1e30f, -1e30f, -1e30f, -1e30f};
  float lrun[4] = {0.f, 0.f, 0.f, 0.f};
  const float scale = 0.08838834764831845f;
  for (int kt = 0; kt <= qt; ++kt) {
    int kv0 = kt << 7;
    __syncthreads();
#pragma unroll
    for (int i = 0; i < 4; ++i) {
      int idx = i * 512 + t;
      int row = idx >> 4, p = idx & 15;
      int col = (p ^ (row & 7)) << 3;
      GLL16(Kb + (long)(kv0 + row) * HDD + col, Ks + (i * 512 + w * 64) * 8);
      GLL16(Vb + (long)row * SS + kv0 + col, Vs + (i * 512 + w * 64) * 8);
    }
    __syncthreads();
    f32x4 sv[8];
#pragma unroll
    for (int n = 0; n < 8; ++n) {
      f32x4 acc = {};
#pragma unroll
      for (int kk = 0; kk < 4; ++kk) {
        int krow = n * 16 + c;
        short8 kf = *(const short8*)(Ks + krow * 128 + ((((kk << 2) | lg) ^ (krow & 7)) << 3));
        acc = __builtin_amdgcn_mfma_f32_16x16x32_bf16(qf[kk], kf, acc, 0, 0, 0);
      }
      sv[n] = acc;
    }
    int qg = q0 + w * 16 + lg * 4;
    if (kt == qt) {
#pragma unroll
      for (int n = 0; n < 8; ++n) {
        int col = kv0 + n * 16 + c;
#pragma unroll
        for (int j = 0; j < 4; ++j) {
          float xv = sv[n][j] * scale;
          sv[n][j] = (col > qg + j) ? -1e30f : xv;
        }
      }
    } else {
#pragma unroll
      for (int n = 0; n < 8; ++n)
#pragma unroll
        for (int j = 0; j < 4; ++j) sv[n][j] *= scale;
    }
    float alpha[4];
#pragma unroll
    for (int j = 0; j < 4; ++j) {
      float mx = sv[0][j];
#pragma unroll
      for (int n = 1; n < 8; ++n) mx = fmaxf(mx, sv[n][j]);
      mx = fmaxf(mx, __shfl_xor(mx, 1));
      mx = fmaxf(mx, __shfl_xor(mx, 2));
      mx = fmaxf(mx, __shfl_xor(mx, 4));
      mx = fmaxf(mx, __shfl_xor(mx, 8));
      float mnew = fmaxf(mrun[j], mx);
      alpha[j] = __expf(mrun[j] - mnew);
      mrun[j] = mnew;
    }
    float rsum[4] = {0.f, 0.f, 0.f, 0.f};
#pragma unroll
    for (int n = 0; n < 8; ++n)
#pragma unroll
      for (int j = 0; j < 4; ++j) {
        float p = __expf(sv[n][j] - mrun[j]);
        sv[n][j] = p;
        rsum[j] += p;
      }
#pragma unroll
    for (int j = 0; j < 4; ++j) {
      rsum[j] += __shfl_xor(rsum[j], 1);
      rsum[j] += __shfl_xor(rsum[j], 2);
      rsum[j] += __shfl_xor(rsum[j], 4);
      rsum[j] += __shfl_xor(rsum[j], 8);
      lrun[j] = lrun[j] * alpha[j] + rsum[j];
    }
#pragma unroll
    for (int n = 0; n < 8; ++n)
#pragma unroll
      for (int j = 0; j < 4; ++j) o[n][j] *= alpha[j];
#pragma unroll
    for (int n = 0; n < 8; ++n)
#pragma unroll
      for (int j = 0; j < 4; ++j) {
        int row = w * 16 + lg * 4 + j;
        int slot = (2 * n + (c >> 3)) ^ (row & 7);
        Ps[row * 128 + slot * 8 + (c & 7)] = f2bf(sv[n][j]);
      }
    __syncthreads();
    short8 pf[4];
    int prow = w * 16 + c;
#pragma unroll
    for (int kk = 0; kk < 4; ++kk)
      pf[kk] = *(const short8*)(Ps + prow * 128 + ((((kk << 2) | lg) ^ (prow & 7)) << 3));
#pragma unroll
    for (int n = 0; n < 8; ++n) {
#pragma unroll
      for (int kk = 0; kk < 4; ++kk) {
        int vrow = n * 16 + c;
        short8 vf = *(const short8*)(Vs + vrow * 128 + ((((kk << 2) | lg) ^ (vrow & 7)) << 3));
        o[n] = __builtin_amdgcn_mfma_f32_16x16x32_bf16(pf[kk], vf, o[n], 0, 0, 0);
      }
    }
  }
  int head = bh & (NHH - 1), b = bh >> 4;
#pragma unroll
  for (int j = 0; j < 4; ++j) {
    float inv = 1.0f / lrun[j];
    int s = q0 + w * 16 + lg * 4 + j;
#pragma unroll
    for (int n = 0; n < 8; ++n) {
      int hcol = head * 128 + n * 16 + c;
      Ob[((long)(b * SS + s)) * HH + hcol] = f2bf(o[n][j] * inv);
    }
  }
}

// ---------------------------------------------------------------------------
extern "C" void kernel_launch(void* const* d_in, const int* in_sizes, int n_in,
                              void* d_out, int out_size, void* d_ws, size_t ws_size,
                              hipStream_t stream) {
  (void)in_sizes; (void)n_in; (void)out_size;
  const float* x     = (const float*)d_in[0];
  const float* wq    = (const float*)d_in[2];
  const float* wk    = (const float*)d_in[3];
  const float* wv    = (const float*)d_in[4];
  const float* wo    = (const float*)d_in[5];
  const float* wgt   = (const float*)d_in[6];
  const float* wup   = (const float*)d_in[7];
  const float* wdn   = (const float*)d_in[8];
  const float* gin   = (const float*)d_in[9];
  const float* gpost = (const float*)d_in[10];
  float* out = (float*)d_out;

  const size_t R0 = 0;
  const size_t R1 = (size_t)32 << 20;
  const size_t R2 = (size_t)48 << 20;
  const size_t R3 = (size_t)112 << 20;
  const size_t NEED = (size_t)176 << 20;
  if (ws_size < NEED) return;

  short* wtq = (short*)((char*)d_ws + R0);  // wtq|wtk|wtv contiguous = QKV concat
  short* wtk = wtq + (size_t)HH * HH;
  short* wtv = wtk + (size_t)HH * HH;
  short* wto = wtv + (size_t)HH * HH;
  short* wtd = (short*)((char*)d_ws + R0);
  short* hb  = (short*)((char*)d_ws + R1);
  short* h2  = hb;
  short* qh  = (short*)((char*)d_ws + R2);  // qh|kh|vt|ab
  short* kh  = qh + (size_t)MM * HH;
  short* vt  = kh + (size_t)MM * HH;
  short* ab  = vt + (size_t)MM * HH;
  short* wtg = (short*)((char*)d_ws + R2);
  short* wtu = wtg + (size_t)HH * FF;
  short* gateb = (short*)((char*)d_ws + R3);

  dim3 b256(256, 1, 1);
  transpose_cast<<<dim3(HH / 32, HH / 32), b256, 0, stream>>>(wq, wtq, HH, HH);
  transpose_cast<<<dim3(HH / 32, HH / 32), b256, 0, stream>>>(wk, wtk, HH, HH);
  transpose_cast<<<dim3(HH / 32, HH / 32), b256, 0, stream>>>(wv, wtv, HH, HH);
  transpose_cast<<<dim3(HH / 32, HH / 32), b256, 0, stream>>>(wo, wto, HH, HH);

  rmsnorm_k<<<dim3(MM), b256, 0, stream>>>(x, gin, hb);

  // fused QKV: N=6144 over contiguous wtq|wtk|wtv; epilogue routes per block
  dim3 gQKV((MM / 128) * (3 * HH / 128), 1, 1);  // 1536 WGs
  gemm_bt<5><<<gQKV, b256, 0, stream>>>(hb, wtq, MM, 3 * HH, HH, qh, nullptr);

  attn_k<<<dim3(SS / 128, BB * NHH), dim3(512, 1, 1), 0, stream>>>(qh, kh, vt, ab);

  dim3 gH((MM / 128) * (HH / 128), 1, 1);  // 512 WGs
  gemm_bt<3><<<gH, b256, 0, stream>>>(ab, wto, MM, HH, HH, out, x);

  transpose_cast<<<dim3(FF / 32, HH / 32), b256, 0, stream>>>(wgt, wtg, HH, FF);
  transpose_cast<<<dim3(FF / 32, HH / 32), b256, 0, stream>>>(wup, wtu, HH, FF);
  transpose_cast<<<dim3(HH / 32, FF / 32), b256, 0, stream>>>(wdn, wtd, FF, HH);

  rmsnorm_k<<<dim3(MM), b256, 0, stream>>>(out, gpost, h2);

  // gate, then silu(gate)*up in-place (R2-proven path)
  dim3 gF((MM / 128) * (FF / 128), 1, 1);  // 2048 WGs
  gemm_bt<0><<<gF, b256, 0, stream>>>(h2, wtg, MM, FF, HH, gateb, nullptr);
  gemm_bt<4><<<gF, b256, 0, stream>>>(h2, wtu, MM, FF, HH, gateb, gateb);

  // down + residual (in-place on d_out)
  gemm_bt<3><<<gH, b256, 0, stream>>>(gateb, wtd, MM, HH, FF, out, out);
}

// Round 8
// 901.800 us; speedup vs baseline: 1.1579x; 1.0137x over previous
//
#include <hip/hip_runtime.h>

// Decoder layer: x -> rms -> QKV -> causal attn -> +x@wo -> rms -> SwiGLU -> +down
// B=2 S=2048 H=2048 NH=16 HD=128 FF=8192, fp32 I/O, bf16 MFMA compute.

#define HH 2048
#define FF 8192
#define BB 2
#define SS 2048
#define NHH 16
#define HDD 128
#define MM (BB * SS)  // 4096 rows

typedef __attribute__((ext_vector_type(8))) short short8;
typedef __attribute__((ext_vector_type(4))) short short4v;
typedef __attribute__((ext_vector_type(4))) float f32x4;

#define DEV __device__ __forceinline__

DEV short f2bf(float f) {  // RNE f32->bf16
  unsigned u = __builtin_bit_cast(unsigned, f);
  u += 0x7fffu + ((u >> 16) & 1u);
  return (short)(u >> 16);
}
DEV float bf2f(short s) {
  unsigned u = ((unsigned)(unsigned short)s) << 16;
  return __builtin_bit_cast(float, u);
}

// async global->LDS, 16B per lane; lds ptr must be wave-uniform, HW adds lane*16
#define GLL16(gp, lp)                                                    \
  __builtin_amdgcn_global_load_lds(                                      \
      (const __attribute__((address_space(1))) void*)(gp),               \
      (__attribute__((address_space(3))) void*)(lp), 16, 0, 0)

// ---------------- transpose+cast tile body: W[K][N] f32 -> Wt[N][K] bf16 ----
// float4 loads (128B/8-lane), short4 stores (64B/8-lane), conflict-free LDS.
DEV void tc_tile(const float* __restrict__ W, short* __restrict__ Wt,
                 int K, int N, int n0, int k0, int t) {
  __shared__ float tile[32][33];
  int r = t >> 3, c4 = (t & 7) << 2;
  f32x4 v = *(const f32x4*)&W[(long)(k0 + r) * N + n0 + c4];
#pragma unroll
  for (int j = 0; j < 4; ++j) tile[r][c4 + j] = v[j];
  __syncthreads();
  short4v o;
#pragma unroll
  for (int j = 0; j < 4; ++j) o[j] = f2bf(tile[c4 + j][r]);
  *(short4v*)&Wt[(long)(n0 + r) * K + k0 + c4] = o;
}

// batch 1: wq,wk,wv,wo (each HHxHH) -> contiguous dst (wtq|wtk|wtv|wto)
__global__ __launch_bounds__(256) void transpose_qkvo(
    const float* __restrict__ wq, const float* __restrict__ wk,
    const float* __restrict__ wv, const float* __restrict__ wo,
    short* __restrict__ dst) {
  int bid = blockIdx.x;              // 4 * 64*64 = 16384 blocks
  int seg = bid >> 12, local = bid & 4095;
  const float* W = seg == 0 ? wq : seg == 1 ? wk : seg == 2 ? wv : wo;
  short* Wt = dst + (size_t)seg * HH * HH;
  int n0 = (local & 63) << 5, k0 = (local >> 6) << 5;
  tc_tile(W, Wt, HH, HH, n0, k0, threadIdx.x);
}

// batch 2: wgt,wup (HHxFF) -> wtg|wtu contiguous; wdn (FFxHH) -> wtd
__global__ __launch_bounds__(256) void transpose_ffn(
    const float* __restrict__ wgt, const float* __restrict__ wup,
    const float* __restrict__ wdn, short* __restrict__ wtg,
    short* __restrict__ wtd) {
  int bid = blockIdx.x;              // 3 * 16384 = 49152 blocks
  int seg = bid >> 14, local = bid & 16383;
  int t = threadIdx.x;
  if (seg < 2) {                     // K=HH, N=FF; 256 x 64 tiles
    const float* W = seg == 0 ? wgt : wup;
    short* Wt = wtg + (size_t)seg * HH * FF;
    int n0 = (local & 255) << 5, k0 = (local >> 8) << 5;
    tc_tile(W, Wt, HH, FF, n0, k0, t);
  } else {                           // wdn: K=FF, N=HH; 64 x 256 tiles
    int n0 = (local & 63) << 5, k0 = (local >> 6) << 5;
    tc_tile(wdn, wtd, FF, HH, n0, k0, t);
  }
}

// ---------------- RMSNorm row kernel: f32 in -> bf16 out --------------------
__global__ __launch_bounds__(256) void rmsnorm_k(const float* __restrict__ x,
                                                 const float* __restrict__ g,
                                                 short* __restrict__ out) {
  int row = blockIdx.x;
  int t = threadIdx.x;
  const float* xr = x + (long)row * HH;
  f32x4 v0 = *(const f32x4*)(xr + t * 4);
  f32x4 v1 = *(const f32x4*)(xr + 1024 + t * 4);
  float ss = v0[0] * v0[0] + v0[1] * v0[1] + v0[2] * v0[2] + v0[3] * v0[3] +
             v1[0] * v1[0] + v1[1] * v1[1] + v1[2] * v1[2] + v1[3] * v1[3];
#pragma unroll
  for (int off = 1; off < 64; off <<= 1) ss += __shfl_xor(ss, off);
  __shared__ float red[4];
  if ((t & 63) == 0) red[t >> 6] = ss;
  __syncthreads();
  float tot = red[0] + red[1] + red[2] + red[3];
  float rs = rsqrtf(tot * (1.0f / HH) + 1e-6f);
  f32x4 g0 = *(const f32x4*)(g + t * 4);
  f32x4 g1 = *(const f32x4*)(g + 1024 + t * 4);
  short4v o0, o1;
#pragma unroll
  for (int e = 0; e < 4; ++e) {
    o0[e] = f2bf(v0[e] * rs * g0[e]);
    o1[e] = f2bf(v1[e] * rs * g1[e]);
  }
  *(short4v*)(out + (long)row * HH + t * 4) = o0;
  *(short4v*)(out + (long)row * HH + 1024 + t * 4) = o1;
}

// ---------------- bf16 MFMA GEMM (m97 128x128, 2-phase) ---------------------
// Block mapping: bijective XCD swizzle + GM=16 grouped supertile (R7: cut
// FETCH 453->164 MB; per-K-step active staging set ~512 KB << 4 MB L2).
// EPI: 0 plain bf16 [M][N]; 1 bf16 per-head [b,h,s,d]; 2 bf16 Vt [b,h,d,s];
//      3 f32 out = aux(f32)[M][N] + acc; 4 bf16 out = silu(aux bf16)*acc;
//      5 QKV concat (N=6144): out base -> qh | kh | vt regions.
template <int EPI>
__global__ __launch_bounds__(256) void gemm_bt(const short* __restrict__ A,
                                               const short* __restrict__ Bt,
                                               int M, int N, int K,
                                               void* out, const void* aux) {
  __shared__ short As[128 * 64];
  __shared__ short Bs[128 * 64];
  int nbn = N >> 7;
  int nwg = gridDim.x;
  int bid = blockIdx.x;
  // bijective XCD swizzle (m204)
  int qq = nwg >> 3, rr = nwg & 7;
  int xcd = bid & 7, lid = bid >> 3;
  int wg = (xcd < rr ? xcd * (qq + 1) : rr * (qq + 1) + (xcd - rr) * qq) + lid;
  // GM-grouped supertile mapping (requires (M/128) % 16 == 0; M=4096 -> 32)
  const int GM = 16;
  int gsz = GM * nbn;
  int gid = wg / gsz, rem = wg % gsz;
  int bm = gid * GM + (rem % GM);
  int bn = rem / GM;
  int t = threadIdx.x, w = t >> 6, lane = t & 63, lg = lane >> 4, c = lane & 15;
  int wr = w >> 1, wc = w & 1;
  const short* Abase = A + (long)bm * 128 * K;
  const short* Bbase = Bt + (long)bn * 128 * K;
  f32x4 acc[4][4] = {};
  int nk = K >> 6;
  for (int kt = 0; kt < nk; ++kt) {
    int k0 = kt << 6;
    __syncthreads();
#pragma unroll
    for (int i = 0; i < 4; ++i) {
      int idx = i * 256 + t;
      int row = idx >> 3, p = idx & 7;
      int col = k0 + ((p ^ (row & 7)) << 3);
      GLL16(Abase + (long)row * K + col, As + (i * 256 + w * 64) * 8);
      GLL16(Bbase + (long)row * K + col, Bs + (i * 256 + w * 64) * 8);
    }
    __syncthreads();
#pragma unroll
    for (int kk = 0; kk < 2; ++kk) {
      short8 af[4], bfr[4];
#pragma unroll
      for (int m = 0; m < 4; ++m) {
        int row = wr * 64 + m * 16 + c;
        af[m] = *(const short8*)(As + row * 64 + ((((kk << 2) | lg) ^ (row & 7)) << 3));
      }
#pragma unroll
      for (int n = 0; n < 4; ++n) {
        int row = wc * 64 + n * 16 + c;
        bfr[n] = *(const short8*)(Bs + row * 64 + ((((kk << 2) | lg) ^ (row & 7)) << 3));
      }
#pragma unroll
      for (int m = 0; m < 4; ++m)
#pragma unroll
        for (int n = 0; n < 4; ++n)
          acc[m][n] = __builtin_amdgcn_mfma_f32_16x16x32_bf16(af[m], bfr[n], acc[m][n], 0, 0, 0);
    }
  }
#pragma unroll
  for (int m = 0; m < 4; ++m) {
#pragma unroll
    for (int n = 0; n < 4; ++n) {
      int rL = wr * 64 + m * 16 + lg * 4;
      int cL = wc * 64 + n * 16 + c;
      long rg = (long)bm * 128 + rL;
      long cg = (long)bn * 128 + cL;
      if (EPI == 2) {
        int b = (int)(rg >> 11), s = (int)(rg & 2047);
        int head = (int)(cg >> 7), d = (int)(cg & 127);
        short4v pk;
#pragma unroll
        for (int j = 0; j < 4; ++j) pk[j] = f2bf(acc[m][n][j]);
        *(short4v*)((short*)out + ((long)(b * NHH + head) * HDD + d) * SS + s) = pk;
      } else if (EPI == 5) {
        short* base = (short*)out;
        int mat = (int)(cg >> 11);         // 0=q, 1=k, 2=v (uniform per block)
        int cc = (int)(cg & 2047);
        int head = cc >> 7, d = cc & 127;
        if (mat == 2) {                    // vt[b*NH+h][d][s], packed 4 s
          int b = (int)(rg >> 11), s = (int)(rg & 2047);
          short4v pk;
#pragma unroll
          for (int j = 0; j < 4; ++j) pk[j] = f2bf(acc[m][n][j]);
          *(short4v*)(base + (size_t)2 * MM * HH +
                      ((long)(b * NHH + head) * HDD + d) * SS + s) = pk;
        } else {                           // q/k: [b*NH+h][s][d]
          short* dst = base + (size_t)mat * MM * HH;
#pragma unroll
          for (int j = 0; j < 4; ++j) {
            long r = rg + j;
            int b = (int)(r >> 11), s = (int)(r & 2047);
            dst[((long)(b * NHH + head) * SS + s) * HDD + d] = f2bf(acc[m][n][j]);
          }
        }
      } else {
#pragma unroll
        for (int j = 0; j < 4; ++j) {
          long r = rg + j;
          float v = acc[m][n][j];
          if (EPI == 0) {
            ((short*)out)[r * N + cg] = f2bf(v);
          } else if (EPI == 1) {
            int b = (int)(r >> 11), s = (int)(r & 2047);
            int head = (int)(cg >> 7), d = (int)(cg & 127);
            ((short*)out)[((long)(b * NHH + head) * SS + s) * HDD + d] = f2bf(v);
          } else if (EPI == 3) {
            ((float*)out)[r * N + cg] = ((const float*)aux)[r * N + cg] + v;
          } else if (EPI == 4) {
            float gv = bf2f(((const short*)aux)[r * N + cg]);
            float sg = gv / (1.0f + __expf(-gv));
            ((short*)out)[r * N + cg] = f2bf(sg * v);
          }
        }
      }
    }
  }
}

// ---------------- causal flash attention -----------------------------------
__global__ __launch_bounds__(512) void attn_k(const short* __restrict__ Qh,
                                              const short* __restrict__ Kh,
                                              const short* __restrict__ Vt,
                                              short* __restrict__ Ob) {
  __shared__ short Qs[128 * 128];
  __shared__ short Ks[128 * 128];
  __shared__ short Vs[128 * 128];
  __shared__ short Ps[128 * 128];
  int qt = blockIdx.x, bh = blockIdx.y;
  int t = threadIdx.x, w = t >> 6, lane = t & 63, lg = lane >> 4, c = lane & 15;
  int q0 = qt << 7;
  const short* Qb = Qh + (long)bh * SS * HDD;
  const short* Kb = Kh + (long)bh * SS * HDD;
  const short* Vb = Vt + (long)bh * HDD * SS;
#pragma unroll
  for (int i = 0; i < 4; ++i) {
    int idx = i * 512 + t;
    int row = idx >> 4, p = idx & 15;
    int col = (p ^ (row & 7)) << 3;
    GLL16(Qb + (long)(q0 + row) * HDD + col, Qs + (i * 512 + w * 64) * 8);
  }
  __syncthreads();
  short8 qf[4];
  int qrow = w * 16 + c;
#pragma unroll
  for (int kk = 0; kk < 4; ++kk)
    qf[kk] = *(const short8*)(Qs + qrow * 128 + ((((kk << 2) | lg) ^ (qrow & 7)) << 3));

  f32x4 o[8] = {};
  float mrun[4] = {-1e30f, -1e30f, -1e30f, -1e30f};
  float lrun[4] = {0.f, 0.f, 0.f, 0.f};
  const float scale = 0.08838834764831845f;
  for (int kt = 0; kt <= qt; ++kt) {
    int kv0 = kt << 7;
    __syncthreads();
#pragma unroll
    for (int i = 0; i < 4; ++i) {
      int idx = i * 512 + t;
      int row = idx >> 4, p = idx & 15;
      int col = (p ^ (row & 7)) << 3;
      GLL16(Kb + (long)(kv0 + row) * HDD + col, Ks + (i * 512 + w * 64) * 8);
      GLL16(Vb + (long)row * SS + kv0 + col, Vs + (i * 512 + w * 64) * 8);
    }
    __syncthreads();
    f32x4 sv[8];
#pragma unroll
    for (int n = 0; n < 8; ++n) {
      f32x4 acc = {};
#pragma unroll
      for (int kk = 0; kk < 4; ++kk) {
        int krow = n * 16 + c;
        short8 kf = *(const short8*)(Ks + krow * 128 + ((((kk << 2) | lg) ^ (krow & 7)) << 3));
        acc = __builtin_amdgcn_mfma_f32_16x16x32_bf16(qf[kk], kf, acc, 0, 0, 0);
      }
      sv[n] = acc;
    }
    int qg = q0 + w * 16 + lg * 4;
    if (kt == qt) {
#pragma unroll
      for (int n = 0; n < 8; ++n) {
        int col = kv0 + n * 16 + c;
#pragma unroll
        for (int j = 0; j < 4; ++j) {
          float xv = sv[n][j] * scale;
          sv[n][j] = (col > qg + j) ? -1e30f : xv;
        }
      }
    } else {
#pragma unroll
      for (int n = 0; n < 8; ++n)
#pragma unroll
        for (int j = 0; j < 4; ++j) sv[n][j] *= scale;
    }
    float alpha[4];
#pragma unroll
    for (int j = 0; j < 4; ++j) {
      float mx = sv[0][j];
#pragma unroll
      for (int n = 1; n < 8; ++n) mx = fmaxf(mx, sv[n][j]);
      mx = fmaxf(mx, __shfl_xor(mx, 1));
      mx = fmaxf(mx, __shfl_xor(mx, 2));
      mx = fmaxf(mx, __shfl_xor(mx, 4));
      mx = fmaxf(mx, __shfl_xor(mx, 8));
      float mnew = fmaxf(mrun[j], mx);
      alpha[j] = __expf(mrun[j] - mnew);
      mrun[j] = mnew;
    }
    float rsum[4] = {0.f, 0.f, 0.f, 0.f};
#pragma unroll
    for (int n = 0; n < 8; ++n)
#pragma unroll
      for (int j = 0; j < 4; ++j) {
        float p = __expf(sv[n][j] - mrun[j]);
        sv[n][j] = p;
        rsum[j] += p;
      }
#pragma unroll
    for (int j = 0; j < 4; ++j) {
      rsum[j] += __shfl_xor(rsum[j], 1);
      rsum[j] += __shfl_xor(rsum[j], 2);
      rsum[j] += __shfl_xor(rsum[j], 4);
      rsum[j] += __shfl_xor(rsum[j], 8);
      lrun[j] = lrun[j] * alpha[j] + rsum[j];
    }
#pragma unroll
    for (int n = 0; n < 8; ++n)
#pragma unroll
      for (int j = 0; j < 4; ++j) o[n][j] *= alpha[j];
#pragma unroll
    for (int n = 0; n < 8; ++n)
#pragma unroll
      for (int j = 0; j < 4; ++j) {
        int row = w * 16 + lg * 4 + j;
        int slot = (2 * n + (c >> 3)) ^ (row & 7);
        Ps[row * 128 + slot * 8 + (c & 7)] = f2bf(sv[n][j]);
      }
    __syncthreads();
    short8 pf[4];
    int prow = w * 16 + c;
#pragma unroll
    for (int kk = 0; kk < 4; ++kk)
      pf[kk] = *(const short8*)(Ps + prow * 128 + ((((kk << 2) | lg) ^ (prow & 7)) << 3));
#pragma unroll
    for (int n = 0; n < 8; ++n) {
#pragma unroll
      for (int kk = 0; kk < 4; ++kk) {
        int vrow = n * 16 + c;
        short8 vf = *(const short8*)(Vs + vrow * 128 + ((((kk << 2) | lg) ^ (vrow & 7)) << 3));
        o[n] = __builtin_amdgcn_mfma_f32_16x16x32_bf16(pf[kk], vf, o[n], 0, 0, 0);
      }
    }
  }
  int head = bh & (NHH - 1), b = bh >> 4;
#pragma unroll
  for (int j = 0; j < 4; ++j) {
    float inv = 1.0f / lrun[j];
    int s = q0 + w * 16 + lg * 4 + j;
#pragma unroll
    for (int n = 0; n < 8; ++n) {
      int hcol = head * 128 + n * 16 + c;
      Ob[((long)(b * SS + s)) * HH + hcol] = f2bf(o[n][j] * inv);
    }
  }
}

// ---------------------------------------------------------------------------
extern "C" void kernel_launch(void* const* d_in, const int* in_sizes, int n_in,
                              void* d_out, int out_size, void* d_ws, size_t ws_size,
                              hipStream_t stream) {
  (void)in_sizes; (void)n_in; (void)out_size;
  const float* x     = (const float*)d_in[0];
  const float* wq    = (const float*)d_in[2];
  const float* wk    = (const float*)d_in[3];
  const float* wv    = (const float*)d_in[4];
  const float* wo    = (const float*)d_in[5];
  const float* wgt   = (const float*)d_in[6];
  const float* wup   = (const float*)d_in[7];
  const float* wdn   = (const float*)d_in[8];
  const float* gin   = (const float*)d_in[9];
  const float* gpost = (const float*)d_in[10];
  float* out = (float*)d_out;

  const size_t R0 = 0;
  const size_t R1 = (size_t)32 << 20;
  const size_t R2 = (size_t)48 << 20;
  const size_t R3 = (size_t)112 << 20;
  const size_t NEED = (size_t)176 << 20;
  if (ws_size < NEED) return;

  short* wtq = (short*)((char*)d_ws + R0);  // wtq|wtk|wtv contiguous = QKV concat
  short* wto = wtq + (size_t)3 * HH * HH;
  short* wtd = (short*)((char*)d_ws + R0);  // reuse after wo-GEMM
  short* hb  = (short*)((char*)d_ws + R1);
  short* h2  = hb;
  short* qh  = (short*)((char*)d_ws + R2);  // qh|kh|vt|ab
  short* kh  = qh + (size_t)MM * HH;
  short* vt  = kh + (size_t)MM * HH;
  short* ab  = vt + (size_t)MM * HH;
  short* wtg = (short*)((char*)d_ws + R2);  // wtg|wtu, reuse after attn+wo
  short* gateb = (short*)((char*)d_ws + R3);

  dim3 b256(256, 1, 1);
  // attention-phase weights -> bf16 [N][K], one fused launch
  transpose_qkvo<<<dim3(16384), b256, 0, stream>>>(wq, wk, wv, wo, wtq);

  rmsnorm_k<<<dim3(MM), b256, 0, stream>>>(x, gin, hb);

  // fused QKV: N=6144 over contiguous wtq|wtk|wtv; epilogue routes per block
  dim3 gQKV((MM / 128) * (3 * HH / 128), 1, 1);  // 1536 WGs
  gemm_bt<5><<<gQKV, b256, 0, stream>>>(hb, wtq, MM, 3 * HH, HH, qh, nullptr);

  attn_k<<<dim3(SS / 128, BB * NHH), dim3(512, 1, 1), 0, stream>>>(qh, kh, vt, ab);

  dim3 gH((MM / 128) * (HH / 128), 1, 1);  // 512 WGs
  gemm_bt<3><<<gH, b256, 0, stream>>>(ab, wto, MM, HH, HH, out, x);

  // MLP-phase weights (R0/R2 now dead), one fused launch
  transpose_ffn<<<dim3(49152), b256, 0, stream>>>(wgt, wup, wdn, wtg, wtd);

  rmsnorm_k<<<dim3(MM), b256, 0, stream>>>(out, gpost, h2);

  // gate, then silu(gate)*up in-place (R2-proven path)
  dim3 gF((MM / 128) * (FF / 128), 1, 1);  // 2048 WGs
  gemm_bt<0><<<gF, b256, 0, stream>>>(h2, wtg, MM, FF, HH, gateb, nullptr);
  gemm_bt<4><<<gF, b256, 0, stream>>>(h2, wtg + (size_t)HH * FF, MM, FF, HH, gateb, gateb);

  // down + residual (in-place on d_out)
  gemm_bt<3><<<gH, b256, 0, stream>>>(gateb, wtd, MM, HH, FF, out, out);
}